// Round 8
// baseline (187.123 us; speedup 1.0000x reference)
//
#include <hip/hip_runtime.h>

// SinePredictor:
//   s = h[edges[0]]; o = h[edges[1]]            [E,128] gathers
//   score = sin(s-o) @ W.T + b                  [E,1]
//   score = softmax over consecutive pairs      [E/2,2] -> [E,1]
//   out = concat(score, score > 0.5)            2*E floats
//
// Evidence ledger:
//   R2 fp32 d_in:                97 us, FETCH 306 MB (3.15 TB/s)
//   R3/R4 bf16-in-ws:          ~163 us score, FETCH 140 MB (0.88 TB/s)
//   R5 fp32 quarter-waves:       90 us, FETCH 303 MB (3.45 TB/s)
//   R6 + sched_barrier(0):       93 us, VGPR still 28 -> barrier no-op;
//     3 fp32 structures all ~3.3 TB/s: per-CU MSHR x latency cap, and
//     303 MB ~= random-graph compulsory floor for fp32 rows on 8 L2s.
//   -> only 2x lever: bf16 rows (floor ~140 MB), blocked by the ws-gather
//      anomaly. Theory: cast kernel's 26 MB of DIRTY L2 lines + per-replay
//      flush poisons the following random reads.
// R8 (= R7 plan, compile-fixed): cast stores NON-TEMPORAL via native
//     ext_vector_type (HIP's ulonglong2 class is rejected by the builtin).
//     Single-variable test of the dirty-writeback theory.

constexpr int   DIMS = 128;
constexpr float TAU  = 0.05f;

typedef unsigned long long ullv2 __attribute__((ext_vector_type(2)));

__device__ __forceinline__ float blo(unsigned int u) {
    union { unsigned int i; float f; } c; c.i = u << 16; return c.f;
}
__device__ __forceinline__ float bhi(unsigned int u) {
    union { unsigned int i; float f; } c; c.i = u & 0xFFFF0000u; return c.f;
}
__device__ __forceinline__ unsigned short f2bf_rne(float f) {
    union { float f; unsigned int i; } c; c.f = f;
    unsigned int r = c.i + 0x7FFFu + ((c.i >> 16) & 1u);
    return (unsigned short)(r >> 16);
}

// 8-element sin-dot from two 16B bf16 fragments.
__device__ __forceinline__ float dot8(const uint4 s, const uint4 o,
                                      const float4 wl, const float4 wh) {
    return __sinf(blo(s.x) - blo(o.x)) * wl.x
         + __sinf(bhi(s.x) - bhi(o.x)) * wl.y
         + __sinf(blo(s.y) - blo(o.y)) * wl.z
         + __sinf(bhi(s.y) - bhi(o.y)) * wl.w
         + __sinf(blo(s.z) - blo(o.z)) * wh.x
         + __sinf(bhi(s.z) - bhi(o.z)) * wh.y
         + __sinf(blo(s.w) - blo(o.w)) * wh.z
         + __sinf(bhi(s.w) - bhi(o.w)) * wh.w;
}

// ---------------- Phase 0: h (fp32) -> hb (bf16), NT stores -----------------
__global__ __launch_bounds__(256) void cast_h_kernel(
    const float* __restrict__ h, unsigned short* __restrict__ hb,
    int n_vec4, int* __restrict__ counter)
{
    if (blockIdx.x == 0 && threadIdx.x == 0) *counter = 0;
    int i = blockIdx.x * blockDim.x + threadIdx.x;
    const int stride = gridDim.x * blockDim.x;
    for (; i < n_vec4; i += stride) {
        const float4 v = reinterpret_cast<const float4*>(h)[i];
        ushort4 o;
        o.x = f2bf_rne(v.x); o.y = f2bf_rne(v.y);
        o.z = f2bf_rne(v.z); o.w = f2bf_rne(v.w);
        ullv2 packed;
        packed.x = ((unsigned long long)o.y << 48) | ((unsigned long long)o.y << 16);
        // build the 128-bit payload correctly: [o.x,o.y,o.z,o.w] little-endian
        packed.x = (unsigned long long)o.x
                 | ((unsigned long long)o.y << 16)
                 | ((unsigned long long)o.z << 32)
                 | ((unsigned long long)o.w << 48);
        packed.y = 0; // lanes write 8 B of payload per 8 bf16? no - see below
        // NOTE: we store 8 bf16 (16 B) per iteration index i, matching the
        // ushort4-per-float4 layout: i indexes float4 of h and ushort4 of hb.
        // ushort4 is 8 B, so pack into ONE 64-bit word and store that.
        __builtin_nontemporal_store(packed.x,
            reinterpret_cast<unsigned long long*>(hb) + i);
    }
}

// ---------------- Phase 1: bf16 scoring + borderline detect -----------------
// Wave = 2 pairs (4 edges). quarter q = lane>>4 -> edge 4c+q.
// Each lane loads uint4 (16 B = 8 bf16): 16 lanes cover the 256 B row.
__global__ __launch_bounds__(256) void score_bf16_kernel(
    const unsigned short* __restrict__ hb,
    const int*   __restrict__ edges,   // [2, E] int32
    const float* __restrict__ W,       // [1, 128]
    const float* __restrict__ b,
    float*       __restrict__ out,     // [2*E]: scores then mask
    int n_edges,
    int* __restrict__ counter, int* __restrict__ list, int list_cap)
{
    const int lane    = threadIdx.x & 63;
    const int sub     = lane & 15;
    const int quarter = lane >> 4;
    const int wave_id = blockIdx.x * (blockDim.x >> 6) + (threadIdx.x >> 6);
    const int n_waves = gridDim.x * (blockDim.x >> 6);
    const int n_pairs = n_edges >> 1;
    const int n_ch    = (n_pairs + 1) >> 1;       // chunks of 2 pairs

    const float4 wl  = reinterpret_cast<const float4*>(W)[sub * 2 + 0];
    const float4 wh  = reinterpret_cast<const float4*>(W)[sub * 2 + 1];
    const float bias = b[0];

    for (int c = wave_id; c < n_ch; c += 2 * n_waves) {
        const int  c2   = c + n_waves;
        const bool has2 = c2 < n_ch;

        const int eA  = 4 * c + quarter;
        const int eAc = min(eA, n_edges - 1);
        const int eB  = has2 ? 4 * c2 + quarter : eAc;
        const int eBc = min(eB, n_edges - 1);

        const int srcA = edges[eAc];
        const int objA = edges[n_edges + eAc];
        const int srcB = edges[eBc];
        const int objB = edges[n_edges + eBc];

        const uint4 sA = *reinterpret_cast<const uint4*>(hb + (size_t)srcA * DIMS + sub * 8);
        const uint4 oA = *reinterpret_cast<const uint4*>(hb + (size_t)objA * DIMS + sub * 8);
        const uint4 sB = *reinterpret_cast<const uint4*>(hb + (size_t)srcB * DIMS + sub * 8);
        const uint4 oB = *reinterpret_cast<const uint4*>(hb + (size_t)objB * DIMS + sub * 8);

        float xA = dot8(sA, oA, wl, wh);
        float xB = dot8(sB, oB, wl, wh);

        #pragma unroll
        for (int m = 8; m >= 1; m >>= 1) xA += __shfl_xor(xA, m, 64);
        #pragma unroll
        for (int m = 8; m >= 1; m >>= 1) xB += __shfl_xor(xB, m, 64);
        xA += bias;
        xB += bias;

        {
            const float other = __shfl_xor(xA, 16, 64);
            const float p = 1.0f / (1.0f + __expf(other - xA));
            if (sub == 0 && eA < n_edges) {
                out[eA]           = p;
                out[n_edges + eA] = (p > 0.5f) ? 1.0f : 0.0f;
            }
            if (sub == 0 && (quarter & 1) == 0 && eA + 1 < n_edges &&
                fabsf(xA - other) < TAU) {
                const int id = atomicAdd(counter, 1);
                if (id < list_cap) list[id] = eA >> 1;
            }
        }
        if (has2) {
            const float other = __shfl_xor(xB, 16, 64);
            const float p = 1.0f / (1.0f + __expf(other - xB));
            if (sub == 0 && eB < n_edges) {
                out[eB]           = p;
                out[n_edges + eB] = (p > 0.5f) ? 1.0f : 0.0f;
            }
            if (sub == 0 && (quarter & 1) == 0 && eB + 1 < n_edges &&
                fabsf(xB - other) < TAU) {
                const int id = atomicAdd(counter, 1);
                if (id < list_cap) list[id] = eB >> 1;
            }
        }
    }
}

// ---------------- Phase 2: fp32 fixup of borderline pairs -------------------
__global__ __launch_bounds__(256) void fixup_kernel(
    const float* __restrict__ h,
    const int*   __restrict__ edges,
    const float* __restrict__ W,
    const float* __restrict__ b,
    float*       __restrict__ out,
    int n_edges,
    const int* __restrict__ counter, const int* __restrict__ list, int list_cap)
{
    const int lane = threadIdx.x & 63;
    const int sub  = lane & 31;
    const int half = lane >> 5;
    const int wave_id = blockIdx.x * (blockDim.x >> 6) + (threadIdx.x >> 6);
    const int n_waves = gridDim.x * (blockDim.x >> 6);

    int cnt = *counter;
    if (cnt > list_cap) cnt = list_cap;

    const float4 w4  = reinterpret_cast<const float4*>(W)[sub];
    const float bias = b[0];

    for (int i = wave_id; i < cnt; i += n_waves) {
        const int pair = list[i];
        const int e    = 2 * pair + half;
        const int src  = edges[e];
        const int obj  = edges[n_edges + e];
        const float4 s4 = reinterpret_cast<const float4*>(h + (size_t)src * DIMS)[sub];
        const float4 o4 = reinterpret_cast<const float4*>(h + (size_t)obj * DIMS)[sub];
        float part = __sinf(s4.x - o4.x) * w4.x
                   + __sinf(s4.y - o4.y) * w4.y
                   + __sinf(s4.z - o4.z) * w4.z
                   + __sinf(s4.w - o4.w) * w4.w;
        #pragma unroll
        for (int m = 16; m >= 1; m >>= 1)
            part += __shfl_xor(part, m, 64);
        const float x     = part + bias;
        const float other = __shfl_xor(x, 32, 64);
        const float p     = 1.0f / (1.0f + __expf(other - x));
        if (sub == 0) {
            out[e]           = p;
            out[n_edges + e] = (p > 0.5f) ? 1.0f : 0.0f;
        }
    }
}

// ---------------- Fallback: R5 fp32 single kernel ---------------------------
__global__ __launch_bounds__(256, 6) void sine_predictor_fp32_kernel(
    const float* __restrict__ h,
    const int*   __restrict__ edges,
    const float* __restrict__ W,
    const float* __restrict__ b,
    float*       __restrict__ out,
    int n_edges)
{
    const int lane    = threadIdx.x & 63;
    const int sub     = lane & 15;
    const int quarter = lane >> 4;
    const int wave_id = blockIdx.x * (blockDim.x >> 6) + (threadIdx.x >> 6);
    const int n_waves = gridDim.x * (blockDim.x >> 6);
    const int n_ch    = (n_edges + 3) >> 2;

    const float4 wl  = reinterpret_cast<const float4*>(W)[sub * 2 + 0];
    const float4 wh  = reinterpret_cast<const float4*>(W)[sub * 2 + 1];
    const float bias = b[0];

    for (int c = wave_id; c < n_ch; c += n_waves) {
        const int e  = 4 * c + quarter;
        const int ec = min(e, n_edges - 1);
        const int src = edges[ec];
        const int obj = edges[n_edges + ec];
        const float4* sr = reinterpret_cast<const float4*>(h + (size_t)src * DIMS);
        const float4* orow = reinterpret_cast<const float4*>(h + (size_t)obj * DIMS);
        const float4 s0 = sr[sub * 2 + 0];
        const float4 s1 = sr[sub * 2 + 1];
        const float4 o0 = orow[sub * 2 + 0];
        const float4 o1 = orow[sub * 2 + 1];
        float x = __sinf(s0.x - o0.x) * wl.x + __sinf(s0.y - o0.y) * wl.y
                + __sinf(s0.z - o0.z) * wl.z + __sinf(s0.w - o0.w) * wl.w
                + __sinf(s1.x - o1.x) * wh.x + __sinf(s1.y - o1.y) * wh.y
                + __sinf(s1.z - o1.z) * wh.z + __sinf(s1.w - o1.w) * wh.w;
        #pragma unroll
        for (int m = 8; m >= 1; m >>= 1) x += __shfl_xor(x, m, 64);
        x += bias;
        const float other = __shfl_xor(x, 16, 64);
        const float p = 1.0f / (1.0f + __expf(other - x));
        if (sub == 0 && e < n_edges) {
            out[e]           = p;
            out[n_edges + e] = (p > 0.5f) ? 1.0f : 0.0f;
        }
    }
}

extern "C" void kernel_launch(void* const* d_in, const int* in_sizes, int n_in,
                              void* d_out, int out_size, void* d_ws, size_t ws_size,
                              hipStream_t stream) {
    const float* h     = (const float*)d_in[0];
    const int*   edges = (const int*)d_in[1];
    const float* W     = (const float*)d_in[2];
    const float* b     = (const float*)d_in[3];
    float*       out   = (float*)d_out;

    const int n_edges = in_sizes[1] / 2;        // edges is [2, E]
    const int n_nodes = in_sizes[0] / DIMS;

    const size_t hb_bytes = (size_t)n_nodes * DIMS * 2;  // bf16 copy of h
    const size_t need     = hb_bytes + 16 + (1u << 20);

    if (ws_size >= need) {
        unsigned short* hb = (unsigned short*)d_ws;
        int* counter = (int*)((char*)d_ws + hb_bytes);
        int* list    = (int*)((char*)d_ws + hb_bytes + 16);
        int list_cap = (int)((ws_size - hb_bytes - 16) / 4);
        if (list_cap > n_edges / 2) list_cap = n_edges / 2;

        cast_h_kernel<<<2048, 256, 0, stream>>>(h, hb, n_nodes * DIMS / 4, counter);
        score_bf16_kernel<<<2048, 256, 0, stream>>>(hb, edges, W, b, out, n_edges,
                                                    counter, list, list_cap);
        fixup_kernel<<<512, 256, 0, stream>>>(h, edges, W, b, out, n_edges,
                                              counter, list, list_cap);
    } else {
        sine_predictor_fp32_kernel<<<1536, 256, 0, stream>>>(h, edges, W, b, out, n_edges);
    }
}

// Round 9
// 91.281 us; speedup vs baseline: 2.0500x; 2.0500x over previous
//
#include <hip/hip_runtime.h>

// SinePredictor:
//   s = h[edges[0]]; o = h[edges[1]]            [E,128] fp32 gathers
//   score = sin(s-o) @ W.T + b                  [E,1]
//   score = softmax over consecutive pairs      [E/2,2] -> [E,1]
//   out = concat(score, score > 0.5)            2*E floats
//
// Evidence ledger:
//   R2 fp32 d_in:              97 us, FETCH 306 MB (3.15 TB/s)
//   R3/R4/R8 bf16-in-ws:     ~162 us, FETCH 143 MB (0.9 TB/s) - NT stores
//     changed nothing; ws random gathers are ~3.8x slower/byte than d_in.
//     Workspace-compression path abandoned.
//   R5 fp32 quarter-waves:     90 us, FETCH 303 MB (3.45 TB/s), VGPR 28
//   R6 + sched_barrier(0):     93 us, VGPR 28 -> scheduler sank loads every
//     time; per-wave MLP never rose. 20 waves/CU x ~2.5 lines x ~575cy MALL
//     latency == 3.4 TB/s equilibrium. Latency-bound theory still untested.
// R9: loop-carried software pipeline (the scheduler CANNOT sink loads across
//     the loop backedge): rows for chunk c+n load while chunk c computes;
//     indices prefetched 2 stages ahead. A/B register rotation, 2x-unrolled,
//     all names static. VGPR_Count >= ~48 is the engagement check.

constexpr int DIMS = 128;

__global__ __launch_bounds__(256) void sine_predictor_kernel(
    const float* __restrict__ h,
    const int*   __restrict__ edges,   // [2, E] int32
    const float* __restrict__ W,       // [1, 128]
    const float* __restrict__ b,       // [1]
    float*       __restrict__ out,     // [2*E]: scores then mask
    int n_edges)
{
    const int lane    = threadIdx.x & 63;
    const int sub     = lane & 15;     // floats sub*8 .. sub*8+7 of the row
    const int quarter = lane >> 4;     // which of 4 consecutive edges
    const int wave_id = blockIdx.x * (blockDim.x >> 6) + (threadIdx.x >> 6);
    const int n       = gridDim.x * (blockDim.x >> 6);   // total waves
    const int n_ch    = (n_edges + 3) >> 2;              // chunks of 4 edges

    const float4 wl  = reinterpret_cast<const float4*>(W)[sub * 2 + 0];
    const float4 wh  = reinterpret_cast<const float4*>(W)[sub * 2 + 1];
    const float bias = b[0];

    // ---- helpers (macros keep every register a named local) ----
    #define LOAD_IDX(ch, iS, iO)                                   \
        {                                                          \
            const int e_  = 4 * (ch) + quarter;                    \
            const int ec_ = min(e_, n_edges - 1);                  \
            iS = edges[ec_];                                       \
            iO = edges[n_edges + ec_];                             \
        }

    #define LOAD_ROWS(iS, iO, s0, s1, o0, o1)                                  \
        {                                                                      \
            const float4* sr_ = reinterpret_cast<const float4*>(h + (size_t)(iS) * DIMS); \
            const float4* or_ = reinterpret_cast<const float4*>(h + (size_t)(iO) * DIMS); \
            s0 = sr_[sub * 2 + 0];                                             \
            s1 = sr_[sub * 2 + 1];                                             \
            o0 = or_[sub * 2 + 0];                                             \
            o1 = or_[sub * 2 + 1];                                             \
        }

    #define COMPUTE_STORE(ch, s0, s1, o0, o1)                                  \
        {                                                                      \
            float x_ = __sinf(s0.x - o0.x) * wl.x + __sinf(s0.y - o0.y) * wl.y \
                     + __sinf(s0.z - o0.z) * wl.z + __sinf(s0.w - o0.w) * wl.w \
                     + __sinf(s1.x - o1.x) * wh.x + __sinf(s1.y - o1.y) * wh.y \
                     + __sinf(s1.z - o1.z) * wh.z + __sinf(s1.w - o1.w) * wh.w;\
            _Pragma("unroll")                                                  \
            for (int m_ = 8; m_ >= 1; m_ >>= 1) x_ += __shfl_xor(x_, m_, 64);  \
            x_ += bias;                                                        \
            const float other_ = __shfl_xor(x_, 16, 64);                       \
            const float p_ = 1.0f / (1.0f + __expf(other_ - x_));              \
            const int e_ = 4 * (ch) + quarter;                                 \
            if (sub == 0 && e_ < n_edges) {                                    \
                out[e_]           = p_;                                        \
                out[n_edges + e_] = (p_ > 0.5f) ? 1.0f : 0.0f;                 \
            }                                                                  \
        }

    int c = wave_id;
    if (c >= n_ch) return;

    // ---- prologue: idx+rows for chunk c (A), idx for chunk c+n (B) ----
    int iS_a, iO_a;
    LOAD_IDX(min(c, n_ch - 1), iS_a, iO_a);
    float4 a_s0, a_s1, a_o0, a_o1;
    LOAD_ROWS(iS_a, iO_a, a_s0, a_s1, a_o0, a_o1);
    int iS_b, iO_b;
    LOAD_IDX(min(c + n, n_ch - 1), iS_b, iO_b);

    while (c < n_ch) {
        // ---- half 1: prefetch B rows (c+n) + A idx (c+2n); compute A (c) ----
        float4 b_s0, b_s1, b_o0, b_o1;
        LOAD_ROWS(iS_b, iO_b, b_s0, b_s1, b_o0, b_o1);
        int iS_a2, iO_a2;
        LOAD_IDX(min(c + 2 * n, n_ch - 1), iS_a2, iO_a2);
        __builtin_amdgcn_sched_barrier(0);
        COMPUTE_STORE(c, a_s0, a_s1, a_o0, a_o1);

        // ---- half 2: prefetch A rows (c+2n) + B idx (c+3n); compute B (c+n) ----
        // a_* values are consumed on the OTHER side of the backedge -> these
        // loads are guaranteed in flight across the next compute phase.
        LOAD_ROWS(iS_a2, iO_a2, a_s0, a_s1, a_o0, a_o1);
        int iS_b2, iO_b2;
        LOAD_IDX(min(c + 3 * n, n_ch - 1), iS_b2, iO_b2);
        __builtin_amdgcn_sched_barrier(0);
        if (c + n < n_ch) {
            COMPUTE_STORE(c + n, b_s0, b_s1, b_o0, b_o1);
        }

        iS_b = iS_b2;
        iO_b = iO_b2;
        c += 2 * n;
    }

    #undef LOAD_IDX
    #undef LOAD_ROWS
    #undef COMPUTE_STORE
}

extern "C" void kernel_launch(void* const* d_in, const int* in_sizes, int n_in,
                              void* d_out, int out_size, void* d_ws, size_t ws_size,
                              hipStream_t stream) {
    const float* h     = (const float*)d_in[0];
    const int*   edges = (const int*)d_in[1];
    const float* W     = (const float*)d_in[2];
    const float* b     = (const float*)d_in[3];
    float*       out   = (float*)d_out;

    const int n_edges = in_sizes[1] / 2;   // edges is [2, E]

    // 2048 blocks x 4 waves = 8192 waves; ~19 chunks per wave, ~10 pipelined
    // iterations - prologue well amortized.
    const int blocks = 2048;
    sine_predictor_kernel<<<blocks, 256, 0, stream>>>(h, edges, W, b, out, n_edges);
}